// Round 7
// baseline (167.747 us; speedup 1.0000x reference)
//
#include <hip/hip_runtime.h>
#include <hip/hip_bf16.h>

// Problem constants
#define BSZ 4
#define CH 64
#define IH 128
#define IW 128
#define PN 63          // number of gaussians
#define PNP 72         // padded weight row (4 zeros each side)
#define TLS 32         // 32x32 outputs per block
#define TLH 36         // extended region for 5x5 halo
#define XSD 40         // staging with halo-of-halo
#define NT 64          // 4 images * 4*4 tiles
#define CG 4           // channels per group
#define NG 16          // channel groups
#define NPOS 324       // 18*18 2x2-position blocks over 36x36
#define NPIX (BSZ*IH*IW)   // 65536

// ---------------------------------------------------------------------------
// Fast gaussian-mixture activation, radius-3 window (7 taps):
//   exp(-(d0-10j)^2/200) = G0 * T^j * C_j.  3 transcendentals total.
//   wp[] is LDS, zero-padded by 4 each side -> no tap masking.
// ---------------------------------------------------------------------------
__device__ __forceinline__ void act_vg(float vv, const float* __restrict__ wp,
                                       float& av, float& ag) {
    float pcf = floorf(__fmaf_rn(vv, 0.1f, 31.5f));
    pcf = fminf(fmaxf(pcf, 0.0f), 62.0f);
    const int pc4 = (int)pcf + 4;
    float d0 = vv - __fmaf_rn(pcf, 10.0f, -310.0f);
    d0 = fminf(fmaxf(d0, -150.0f), 150.0f);
    const float G0 = __expf(d0 * d0 * -0.005f);
    const float T  = __expf(d0 * 0.1f);
    const float Ti = __expf(d0 * -0.1f);
    float t0 = wp[pc4] * G0;
    float accv = t0, accg = t0 * d0;
    float Tp = T, Tm = Ti;
    float gc = G0 * 0.60653066f;
    float tp = wp[pc4 + 1] * (gc * Tp), tm = wp[pc4 - 1] * (gc * Tm);
    accv += tp + tm;
    accg = __fmaf_rn(tp, d0 - 10.0f, __fmaf_rn(tm, d0 + 10.0f, accg));
    Tp *= T; Tm *= Ti;
    gc = G0 * 0.13533528f;
    tp = wp[pc4 + 2] * (gc * Tp); tm = wp[pc4 - 2] * (gc * Tm);
    accv += tp + tm;
    accg = __fmaf_rn(tp, d0 - 20.0f, __fmaf_rn(tm, d0 + 20.0f, accg));
    Tp *= T; Tm *= Ti;
    gc = G0 * 0.011108997f;
    tp = wp[pc4 + 3] * (gc * Tp); tm = wp[pc4 - 3] * (gc * Tm);
    accv += tp + tm;
    accg = __fmaf_rn(tp, d0 - 30.0f, __fmaf_rn(tm, d0 + 30.0f, accg));
    av = accv;
    ag = accg * -0.01f;
}

__device__ __forceinline__ float act_v(float vv, const float* __restrict__ wp) {
    float pcf = floorf(__fmaf_rn(vv, 0.1f, 31.5f));
    pcf = fminf(fmaxf(pcf, 0.0f), 62.0f);
    const int pc4 = (int)pcf + 4;
    float d0 = vv - __fmaf_rn(pcf, 10.0f, -310.0f);
    d0 = fminf(fmaxf(d0, -150.0f), 150.0f);
    const float G0 = __expf(d0 * d0 * -0.005f);
    const float T  = __expf(d0 * 0.1f);
    const float Ti = __expf(d0 * -0.1f);
    float accv = wp[pc4] * G0;
    float Tp = T, Tm = Ti;
    accv += G0 * 0.60653066f  * (wp[pc4 + 1] * Tp + wp[pc4 - 1] * Tm);
    Tp *= T; Tm *= Ti;
    accv += G0 * 0.13533528f  * (wp[pc4 + 2] * Tp + wp[pc4 - 2] * Tm);
    Tp *= T; Tm *= Ti;
    accv += G0 * 0.011108997f * (wp[pc4 + 3] * Tp + wp[pc4 - 3] * Tm);
    return accv;
}

// ---------------------------------------------------------------------------
// kAB: per block (tile, 4-channel group):
//   phase 1: a0/g0 on ext 36x36 via 2x2 register tiles (6x6 window serves
//            4 outputs x 25 taps x 4 channels). rep_pad == per-output
//            clamped centers. a0 -> LDS, g0 -> global bf16 (interior only).
//   phase 2: partial c1 = sum_cc f1_cc (*) a0_cc, 2x2/thread, atomicAdd
//            into the memset-zeroed c1acc plane.
// ---------------------------------------------------------------------------
__global__ __launch_bounds__(256) void kAB(const float* __restrict__ x,
                                           const float* __restrict__ f0,
                                           const float* __restrict__ b0,
                                           const float* __restrict__ w0,
                                           const float* __restrict__ f1,
                                           float* __restrict__ c1acc,
                                           __hip_bfloat16* __restrict__ g0out) {
    __shared__ float xs[XSD * XSD];          // 6.4 KB
    __shared__ float a0s[CG][TLH * TLH];     // 20.7 KB
    __shared__ float w0ps[CG][PNP];          // 1.2 KB

    const int tile = blockIdx.x;
    const int cgi  = blockIdx.y;
    const int cg   = cgi * CG;
    const int b    = tile >> 4;
    const int t    = tile & 15;
    const int h0   = (t >> 2) * TLS;
    const int w0p  = (t & 3) * TLS;
    const int tid  = threadIdx.x;

    for (int i = tid; i < XSD * XSD; i += 256) {
        int iy = i / XSD, ix = i - iy * XSD;
        int gy = min(max(h0 + iy - 4, 0), IH - 1);
        int gx = min(max(w0p + ix - 4, 0), IW - 1);
        xs[i] = x[((size_t)b * IH + gy) * IW + gx] * 255.0f;
    }
    for (int i = tid; i < CG * PNP; i += 256) {
        int cc = i / PNP, k = i - cc * PNP;
        float v = 0.0f;
        if (k >= 4 && k < 4 + PN) v = w0[(size_t)(cg + cc) * PN + (k - 4)];
        w0ps[cc][k] = v;
    }
    __syncthreads();

    // phase 1: conv0 + act on 2x2 position blocks
    for (int p = tid; p < NPOS; p += 256) {
        const int pyb = p / 18, pxb = p - pyb * 18;
        const int py = 2 * pyb, px = 2 * pxb;
        const int gy0 = h0 + py - 2, gx0 = w0p + px - 2;
        const int gy1 = gy0 + 1,     gx1 = gx0 + 1;
        const int gyc0 = min(max(gy0, 0), IH - 1), gyc1 = min(max(gy1, 0), IH - 1);
        const int gxc0 = min(max(gx0, 0), IW - 1), gxc1 = min(max(gx1, 0), IW - 1);
        const int cy0 = gyc0 - h0 + 4, cx0 = gxc0 - w0p + 4;
        const int ry1 = (gyc1 - h0 + 4) - cy0;     // 0 or 1
        const int rx1 = (gxc1 - w0p + 4) - cx0;    // 0 or 1
        const bool iny0 = (gy0 == gyc0), iny1 = (gy1 == gyc1);
        const bool inx0 = (gx0 == gxc0), inx1 = (gx1 == gxc1);

        float win[6][6];
#pragma unroll
        for (int r = 0; r < 6; ++r)
#pragma unroll
            for (int c = 0; c < 6; ++c)
                win[r][c] = xs[(cy0 - 2 + r) * XSD + cx0 - 2 + c];

        for (int cc = 0; cc < CG; ++cc) {
            const int c = cg + cc;
            const float bias = b0[c];
            float a00 = bias, a01 = bias, a10 = bias, a11 = bias;
#pragma unroll
            for (int u = 0; u < 5; ++u)
#pragma unroll
                for (int v = 0; v < 5; ++v) {
                    const float kv = f0[(size_t)c * 25 + u * 5 + v];
                    a00 = __fmaf_rn(win[u][v],             kv, a00);
                    a01 = __fmaf_rn(win[u][rx1 + v],       kv, a01);
                    a10 = __fmaf_rn(win[ry1 + u][v],       kv, a10);
                    a11 = __fmaf_rn(win[ry1 + u][rx1 + v], kv, a11);
                }
            float av, ag;
            const size_t gb = ((size_t)b * CH + c) * (IH * IW);
            act_vg(a00, w0ps[cc], av, ag);
            a0s[cc][py * TLH + px] = av;
            if (iny0 && inx0) g0out[gb + gy0 * IW + gx0] = __float2bfloat16(ag);
            act_vg(a01, w0ps[cc], av, ag);
            a0s[cc][py * TLH + px + 1] = av;
            if (iny0 && inx1) g0out[gb + gy0 * IW + gx1] = __float2bfloat16(ag);
            act_vg(a10, w0ps[cc], av, ag);
            a0s[cc][(py + 1) * TLH + px] = av;
            if (iny1 && inx0) g0out[gb + gy1 * IW + gx0] = __float2bfloat16(ag);
            act_vg(a11, w0ps[cc], av, ag);
            a0s[cc][(py + 1) * TLH + px + 1] = av;
            if (iny1 && inx1) g0out[gb + gy1 * IW + gx1] = __float2bfloat16(ag);
        }
    }
    __syncthreads();

    // phase 2: partial c1, 2x2/thread, atomic into c1acc
    const int lx = tid & 15, ly = tid >> 4;
    const int r0 = 2 * ly, c0 = 2 * lx;
    float a00 = 0.f, a01 = 0.f, a10 = 0.f, a11 = 0.f;

#pragma unroll
    for (int cc = 0; cc < CG; ++cc) {
        float win[6][6];
#pragma unroll
        for (int r = 0; r < 6; ++r) {
            const float2* rp = (const float2*)&a0s[cc][(r0 + r) * TLH + c0];
            float2 p0 = rp[0], p1 = rp[1], p2 = rp[2];
            win[r][0] = p0.x; win[r][1] = p0.y; win[r][2] = p1.x;
            win[r][3] = p1.y; win[r][4] = p2.x; win[r][5] = p2.y;
        }
#pragma unroll
        for (int u = 0; u < 5; ++u)
#pragma unroll
            for (int v = 0; v < 5; ++v) {
                const float kv = f1[(size_t)(cg + cc) * 25 + u * 5 + v];
                a00 = __fmaf_rn(win[u][v],         kv, a00);
                a01 = __fmaf_rn(win[u][v + 1],     kv, a01);
                a10 = __fmaf_rn(win[u + 1][v],     kv, a10);
                a11 = __fmaf_rn(win[u + 1][v + 1], kv, a11);
            }
    }

    const size_t pix = ((size_t)b * IH + h0 + r0) * IW + w0p + c0;
    atomicAdd(&c1acc[pix],          a00);
    atomicAdd(&c1acc[pix + 1],      a01);
    atomicAdd(&c1acc[pix + IW],     a10);
    atomicAdd(&c1acc[pix + IW + 1], a11);
}

// ---------------------------------------------------------------------------
// kB2: a1 = act(b1 + c1acc, w1);  out_init = x - exp(lam)*(x-y)
// ---------------------------------------------------------------------------
__global__ __launch_bounds__(256) void kB2(const float* __restrict__ c1acc,
                                           const float* __restrict__ b1,
                                           const float* __restrict__ w1,
                                           const float* __restrict__ x,
                                           const float* __restrict__ y,
                                           const float* __restrict__ lam_param,
                                           float* __restrict__ a1,
                                           float* __restrict__ out) {
    __shared__ float w1p[PNP];
    const int tid = threadIdx.x;
    if (tid < PNP) {
        float v = 0.0f;
        if (tid >= 4 && tid < 4 + PN) v = w1[tid - 4];
        w1p[tid] = v;
    }
    __syncthreads();

    const int pid = blockIdx.x * 256 + tid;
    a1[pid] = act_v(b1[0] + c1acc[pid], w1p);

    const float elam = __expf(lam_param[0]);
    const float xv = x[pid], yv = y[pid];
    out[pid] = xv - elam * (xv - yv);
}

// ---------------------------------------------------------------------------
// kCD: per block (tile, 4-channel group):
//   phase 1: dbuf_cc = conv_t5(a1) * g0 on ext 36x36 via 2x2 register tiles
//   phase 2: partial d3 = sum_cc f0_cc full-corr dbuf_cc, 2x2/thread,
//            atomicAdd(-d3/255) into out (pre-initialized by kB2).
// ---------------------------------------------------------------------------
__global__ __launch_bounds__(256) void kCD(const float* __restrict__ a1,
                                           const float* __restrict__ f1,
                                           const float* __restrict__ f0,
                                           const __hip_bfloat16* __restrict__ g0,
                                           float* __restrict__ out) {
    __shared__ float a1s[XSD * XSD];         // 6.4 KB
    __shared__ float dbs[CG][TLH * TLH];     // 20.7 KB

    const int tile = blockIdx.x;
    const int cgi  = blockIdx.y;
    const int cg   = cgi * CG;
    const int b    = tile >> 4;
    const int t    = tile & 15;
    const int h0   = (t >> 2) * TLS;
    const int w0p  = (t & 3) * TLS;
    const int tid  = threadIdx.x;

    for (int p = tid; p < XSD * XSD; p += 256) {
        int iy = p / XSD, ix = p - iy * XSD;
        int gy = h0 + iy - 4, gx = w0p + ix - 4;
        float v = 0.0f;
        if ((unsigned)gy < IH && (unsigned)gx < IW)
            v = a1[((size_t)b * IH + gy) * IW + gx];
        a1s[p] = v;
    }
    __syncthreads();

    // phase 1: conv_t * g0 on 2x2 position blocks
    for (int p = tid; p < NPOS; p += 256) {
        const int pyb = p / 18, pxb = p - pyb * 18;
        const int py = 2 * pyb, px = 2 * pxb;
        const int gy0 = h0 + py - 2, gx0 = w0p + px - 2;
        const bool iny0 = (unsigned)gy0 < IH, iny1 = (unsigned)(gy0 + 1) < IH;
        const bool inx0 = (unsigned)gx0 < IW, inx1 = (unsigned)(gx0 + 1) < IW;

        float win[6][6];
#pragma unroll
        for (int r = 0; r < 6; ++r) {
            const float2* rp = (const float2*)&a1s[(py + r) * XSD + px];
            float2 p0 = rp[0], p1 = rp[1], p2 = rp[2];
            win[r][0] = p0.x; win[r][1] = p0.y; win[r][2] = p1.x;
            win[r][3] = p1.y; win[r][4] = p2.x; win[r][5] = p2.y;
        }

        for (int cc = 0; cc < CG; ++cc) {
            const int c = cg + cc;
            float d00 = 0.f, d01 = 0.f, d10 = 0.f, d11 = 0.f;
#pragma unroll
            for (int u = 0; u < 5; ++u)
#pragma unroll
                for (int v = 0; v < 5; ++v) {
                    const float kv = f1[(size_t)c * 25 + u * 5 + v];
                    d00 = __fmaf_rn(win[4 - u][4 - v], kv, d00);
                    d01 = __fmaf_rn(win[4 - u][5 - v], kv, d01);
                    d10 = __fmaf_rn(win[5 - u][4 - v], kv, d10);
                    d11 = __fmaf_rn(win[5 - u][5 - v], kv, d11);
                }
            const size_t gb = ((size_t)b * CH + c) * (IH * IW);
            float o00 = 0.f, o01 = 0.f, o10 = 0.f, o11 = 0.f;
            if (iny0 && inx0) o00 = d00 * __bfloat162float(g0[gb + gy0 * IW + gx0]);
            if (iny0 && inx1) o01 = d01 * __bfloat162float(g0[gb + gy0 * IW + gx0 + 1]);
            if (iny1 && inx0) o10 = d10 * __bfloat162float(g0[gb + (gy0 + 1) * IW + gx0]);
            if (iny1 && inx1) o11 = d11 * __bfloat162float(g0[gb + (gy0 + 1) * IW + gx0 + 1]);
            dbs[cc][py * TLH + px]           = o00;
            dbs[cc][py * TLH + px + 1]       = o01;
            dbs[cc][(py + 1) * TLH + px]     = o10;
            dbs[cc][(py + 1) * TLH + px + 1] = o11;
        }
    }
    __syncthreads();

    // phase 2: partial d3, 2x2/thread, atomic into out
    const int lx = tid & 15, ly = tid >> 4;
    const int r0 = 2 * ly, c0 = 2 * lx;
    float a00 = 0.f, a01 = 0.f, a10 = 0.f, a11 = 0.f;

#pragma unroll
    for (int cc = 0; cc < CG; ++cc) {
        float win[6][6];
#pragma unroll
        for (int r = 0; r < 6; ++r) {
            const float2* rp = (const float2*)&dbs[cc][(r0 + r) * TLH + c0];
            float2 p0 = rp[0], p1 = rp[1], p2 = rp[2];
            win[r][0] = p0.x; win[r][1] = p0.y; win[r][2] = p1.x;
            win[r][3] = p1.y; win[r][4] = p2.x; win[r][5] = p2.y;
        }
#pragma unroll
        for (int u = 0; u < 5; ++u)
#pragma unroll
            for (int v = 0; v < 5; ++v) {
                const float kv = f0[(size_t)(cg + cc) * 25 + u * 5 + v];
                a00 = __fmaf_rn(win[4 - u][4 - v], kv, a00);
                a01 = __fmaf_rn(win[4 - u][5 - v], kv, a01);
                a10 = __fmaf_rn(win[5 - u][4 - v], kv, a10);
                a11 = __fmaf_rn(win[5 - u][5 - v], kv, a11);
            }
    }

    const size_t pix = ((size_t)b * IH + h0 + r0) * IW + w0p + c0;
    const float s = -1.0f / 255.0f;
    atomicAdd(&out[pix],          a00 * s);
    atomicAdd(&out[pix + 1],      a01 * s);
    atomicAdd(&out[pix + IW],     a10 * s);
    atomicAdd(&out[pix + IW + 1], a11 * s);
}

// ---------------------------------------------------------------------------
extern "C" void kernel_launch(void* const* d_in, const int* in_sizes, int n_in,
                              void* d_out, int out_size, void* d_ws, size_t ws_size,
                              hipStream_t stream) {
    const float* x   = (const float*)d_in[0];
    const float* y   = (const float*)d_in[1];
    // d_in[2] = lam (ignored by reference)
    const float* f0  = (const float*)d_in[3];
    const float* b0  = (const float*)d_in[4];
    const float* f1  = (const float*)d_in[5];
    const float* b1  = (const float*)d_in[6];
    const float* w0  = (const float*)d_in[7];
    const float* w1  = (const float*)d_in[8];
    const float* lam = (const float*)d_in[9];
    float* out = (float*)d_out;

    const size_t nch = (size_t)BSZ * CH * IH * IW;   // 4.19M elements
    __hip_bfloat16* g0 = (__hip_bfloat16*)d_ws;      // 8.4 MB (bf16)
    float* c1acc = (float*)(g0 + nch);               // 0.26 MB
    float* a1    = c1acc + NPIX;                     // 0.26 MB

    hipMemsetAsync(c1acc, 0, NPIX * sizeof(float), stream);
    kAB<<<dim3(NT, NG), 256, 0, stream>>>(x, f0, b0, w0, f1, c1acc, g0);
    kB2<<<NPIX / 256, 256, 0, stream>>>(c1acc, b1, w1, x, y, lam, a1, out);
    kCD<<<dim3(NT, NG), 256, 0, stream>>>(a1, f1, f0, g0, out);
}